// Round 7
// baseline (341.316 us; speedup 1.0000x reference)
//
#include <hip/hip_runtime.h>
#include <cstdint>
#include <cmath>

#define T_TOK 1024
#define H_DIM 1024
#define E_NUM 32
#define I_DIM 512
#define IS_DIM 2048
#define NCOL_R 16384
#define NCOL_T 18432
#define SCALE_F 2.5f
#define MAXTILES 96

typedef __bf16 bf16x8 __attribute__((ext_vector_type(8)));
typedef float f32x4 __attribute__((ext_vector_type(4)));

typedef __attribute__((address_space(3))) unsigned int lds_u32_t;
typedef __attribute__((address_space(1))) const unsigned int glb_u32_t;

__device__ __forceinline__ unsigned short f2b(float f) {
    union { float f; uint32_t u; } v; v.f = f;
    return (unsigned short)((v.u + 0x7FFFu + ((v.u >> 16) & 1u)) >> 16);
}

// 2x fp32 -> packed 2x bf16, RNE (identical rounding to f2b). gfx950 HW op.
__device__ __forceinline__ uint32_t cvt2(float lo, float hi) {
    uint32_t r;
    asm("v_cvt_pk_bf16_f32 %0, %1, %2" : "=v"(r) : "v"(lo), "v"(hi));
    return r;
}

__device__ __forceinline__ void gll16(const unsigned short* g, unsigned short* l) {
    __builtin_amdgcn_global_load_lds((glb_u32_t*)g, (lds_u32_t*)l, 16, 0, 0);
}

// ================= lane-parallel routing: one wave per token =================
__device__ __forceinline__ void routing_wave(const float* __restrict__ x,
                                             const float* __restrict__ gate_w,
                                             const float* __restrict__ e_bias,
                                             float* __restrict__ combine,
                                             int* __restrict__ topk, int t) {
    int l = threadIdx.x & 63;
    int e = l & 31, half = l >> 5;
    const float4* xr = reinterpret_cast<const float4*>(x + (size_t)t * H_DIM + half * 512);
    const float4* wr = reinterpret_cast<const float4*>(gate_w + (size_t)e * H_DIM + half * 512);
    float s = 0.f;
#pragma unroll 8
    for (int j = 0; j < 128; j++) {
        float4 a = xr[j], b = wr[j];
        s += a.x * b.x + a.y * b.y + a.z * b.z + a.w * b.w;
    }
    s += __shfl_xor(s, 32);            // lanes 0..31 (dup in 32..63) hold logit[e]
    float sg = 1.f / (1.f + expf(-s));
    float swb = sg + e_bias[e];
    // group top-2 sum (group = 4 consecutive experts; pairing-invariant formula)
    float v1 = __shfl_xor(swb, 1), v2 = __shfl_xor(swb, 2), v3 = __shfl_xor(swb, 3);
    float hi01 = fmaxf(swb, v1), lo01 = fminf(swb, v1);
    float hi23 = fmaxf(v2, v3),  lo23 = fminf(v2, v3);
    float gs = fmaxf(hi01, hi23) + fmaxf(fminf(hi01, hi23), fmaxf(lo01, lo23));
    int g = e >> 2;
    int grank = 0;
#pragma unroll
    for (int gg = 0; gg < 8; gg++) {
        float og = __shfl(gs, gg * 4);
        grank += ((og > gs) || (og == gs && gg < g)) ? 1 : 0;
    }
    bool gsel = grank < 4;
    float candv = gsel ? swb : 0.0f;
    int erank = 0;
#pragma unroll
    for (int ee = 0; ee < 32; ee++) {
        float oc = __shfl(candv, ee);
        erank += ((oc > candv) || (oc == candv && ee < e)) ? 1 : 0;
    }
    bool esel = (erank < 8) && (half == 0);   // exactly 8 lanes (total order)
    unsigned long long m = __ballot(esel);
    int idx = __popcll(m & ((1ull << l) - 1ull));
    if (esel) topk[t * 8 + idx] = e;
    float r = esel ? sg : 0.f;
#pragma unroll
    for (int off = 1; off < 64; off <<= 1) r += __shfl_xor(r, off);
    float inv = SCALE_F / (r + 1e-20f);
    if (half == 0) combine[t * E_NUM + e] = esel ? sg * inv : 0.0f;
}

// ================= prep1: routing + x-cvt only (weights go direct-fp32) =================
// blocks [0,256): routing (4 tok/blk) | [256,512): cvt_x
__global__ __launch_bounds__(256)
void prep1_kernel(const float* __restrict__ x, const float* __restrict__ gate_w,
                  const float* __restrict__ e_bias,
                  unsigned short* __restrict__ xb, float* __restrict__ combine,
                  int* __restrict__ topk) {
    int b = blockIdx.x;
    if (b < 256) {
        int t = b * 4 + (threadIdx.x >> 6);
        routing_wave(x, gate_w, e_bias, combine, topk, t);
        return;
    }
    int bb = b - 256;
#pragma unroll
    for (int p = 0; p < 4; p++) {
        int i = bb * 1024 + p * 256 + threadIdx.x;
        float4 v = reinterpret_cast<const float4*>(x)[i];
        uint2 o;
        o.x = cvt2(v.x, v.y);
        o.y = cvt2(v.z, v.w);
        reinterpret_cast<uint2*>(xb)[i] = o;
    }
}

// ---------------- build expert segments (single block, 1024 threads) ----------------
__global__ __launch_bounds__(1024)
void listbuild_kernel(const int* __restrict__ topk, int* __restrict__ meta,
                      int* __restrict__ pair_token, int* __restrict__ slot_of) {
    __shared__ int cnt[E_NUM], start[E_NUM], fill[E_NUM];
    int t = threadIdx.x;
    if (t < E_NUM) cnt[t] = 0;
    __syncthreads();
    int ids[8];
#pragma unroll
    for (int r = 0; r < 8; r++) {
        ids[r] = topk[t * 8 + r];
        atomicAdd(&cnt[ids[r]], 1);
    }
    __syncthreads();
    if (t == 0) {
        int acc = 0;
        for (int e = 0; e < E_NUM; e++) {
            int nt = (cnt[e] + 127) >> 7;
            start[e] = acc * 128;
            fill[e] = 0;
            for (int j = 0; j < nt; j++) meta[1 + acc + j] = e;
            acc += nt;
        }
        meta[0] = acc;
    }
    __syncthreads();
    for (int i = t; i < MAXTILES * 128; i += 1024) pair_token[i] = 0;
    __syncthreads();
#pragma unroll
    for (int r = 0; r < 8; r++) {
        int e = ids[r];
        int s = start[e] + atomicAdd(&fill[e], 1);
        pair_token[s] = t;
        slot_of[t * 8 + r] = s;
    }
}

// ================= fused gate/up, direct-fp32 B, 128x64 tiles =================
// blocks [0,768): routed (tile = b>>3, ci64 = b&7) | [768,1024): shared (row128 x ci64)
// B: float2 loads (2 consec n / thread), cvt_pk, single-buffered LDS [64][40].
// A: double-buffered global_load_lds. 2 barriers per k-step.
__global__ __launch_bounds__(256, 4)
void gateup_fused(const unsigned short* __restrict__ xb,
                  const float* __restrict__ w_gate,
                  const float* __restrict__ w_up,
                  const float* __restrict__ ws_gate,
                  const float* __restrict__ ws_up,
                  const float* __restrict__ combine,
                  const int* __restrict__ pair_token,
                  const int* __restrict__ meta,
                  unsigned short* __restrict__ act_s,
                  unsigned short* __restrict__ act_sh) {
    int b = blockIdx.x;
    bool routed = b < 768;
    int tid = threadIdx.x, lane = tid & 63, w = tid >> 6;
    int wr = w >> 1, wc = w & 1;
    __shared__ __align__(16) unsigned short lA[2][128 * 32];
    __shared__ __align__(16) unsigned short lBg[64 * 40];
    __shared__ __align__(16) unsigned short lBu[64 * 40];

    int srow = w * 32 + (lane >> 2);
    int schunk = (lane & 3) * 8;
    int aoff = (w * 32) * 32;
    int nc = (tid & 31) * 2;       // B col pair within 64
    int kg = tid >> 5;             // 0..7, owns k rows kg*4..kg*4+3

    const unsigned short *gA0, *gA1;
    const float *gBg, *gBu;
    int bstride;
    int e = 0, slot0 = 0, row0 = 0, ci0 = 0;
    if (routed) {
        int tile = b >> 3;
        if (tile >= meta[0]) return;
        e = meta[1 + tile];
        ci0 = (b & 7) * 64;
        slot0 = tile * 128;
        int tok0 = pair_token[slot0 + srow];
        int tok1 = pair_token[slot0 + srow + 16];
        gA0 = xb + (size_t)tok0 * H_DIM + schunk;
        gA1 = xb + (size_t)tok1 * H_DIM + schunk;
        gBg = w_gate + (size_t)e * H_DIM * I_DIM + ci0;
        gBu = w_up   + (size_t)e * H_DIM * I_DIM + ci0;
        bstride = I_DIM;
    } else {
        int bb = b - 768;
        row0 = (bb >> 5) * 128;
        ci0 = (bb & 31) * 64;
        gA0 = xb + (size_t)(row0 + srow) * H_DIM + schunk;
        gA1 = gA0 + 16 * H_DIM;
        gBg = ws_gate + ci0;
        gBu = ws_up + ci0;
        bstride = IS_DIM;
    }

    f32x4 accg[4][2], accu[4][2];
#pragma unroll
    for (int i = 0; i < 4; i++)
#pragma unroll
        for (int j = 0; j < 2; j++)
#pragma unroll
            for (int r = 0; r < 4; r++) { accg[i][j][r] = 0.f; accu[i][j][r] = 0.f; }

    float2 vg[4], vu[4];

#define GU_LOADB(KK)                                                    \
    do {                                                                \
        size_t kb = (size_t)((KK) * 32 + kg * 4);                       \
        _Pragma("unroll")                                               \
        for (int j = 0; j < 4; j++) {                                   \
            vg[j] = *reinterpret_cast<const float2*>(&gBg[(kb + j) * bstride + nc]); \
            vu[j] = *reinterpret_cast<const float2*>(&gBu[(kb + j) * bstride + nc]); \
        }                                                               \
    } while (0)

#define GU_GLLA(KK, BSEL)                                               \
    do {                                                                \
        int _k0 = (KK) * 32;                                            \
        unsigned short* _a = &lA[BSEL][aoff];                           \
        gll16(gA0 + _k0, _a);                                           \
        gll16(gA1 + _k0, _a + 16 * 32);                                 \
    } while (0)

#define GU_WRB()                                                        \
    do {                                                                \
        uint2 u;                                                        \
        u.x = cvt2(vg[0].x, vg[1].x); u.y = cvt2(vg[2].x, vg[3].x);     \
        *reinterpret_cast<uint2*>(&lBg[nc * 40 + kg * 4]) = u;          \
        u.x = cvt2(vg[0].y, vg[1].y); u.y = cvt2(vg[2].y, vg[3].y);     \
        *reinterpret_cast<uint2*>(&lBg[(nc + 1) * 40 + kg * 4]) = u;    \
        u.x = cvt2(vu[0].x, vu[1].x); u.y = cvt2(vu[2].x, vu[3].x);     \
        *reinterpret_cast<uint2*>(&lBu[nc * 40 + kg * 4]) = u;          \
        u.x = cvt2(vu[0].y, vu[1].y); u.y = cvt2(vu[2].y, vu[3].y);     \
        *reinterpret_cast<uint2*>(&lBu[(nc + 1) * 40 + kg * 4]) = u;    \
    } while (0)

    GU_GLLA(0, 0);
    GU_LOADB(0);
    __syncthreads();          // A(0) in LDS, B(0) loads drained
    GU_WRB();                 // B(0) -> LDS
    __syncthreads();
    for (int kk = 0; kk < 32; kk++) {
        int cur = kk & 1;
        if (kk < 31) { GU_GLLA(kk + 1, cur ^ 1); GU_LOADB(kk + 1); }
        bf16x8 af[4], bgf[2], buf2[2];
#pragma unroll
        for (int mi = 0; mi < 4; mi++)
            af[mi] = *reinterpret_cast<const bf16x8*>(
                &lA[cur][(wr * 64 + mi * 16 + (lane & 15)) * 32 + (lane >> 4) * 8]);
#pragma unroll
        for (int ni = 0; ni < 2; ni++) {
            int nn = (wc * 32 + ni * 16 + (lane & 15)) * 40 + (lane >> 4) * 8;
            bgf[ni] = *reinterpret_cast<const bf16x8*>(&lBg[nn]);
            buf2[ni] = *reinterpret_cast<const bf16x8*>(&lBu[nn]);
        }
#pragma unroll
        for (int mi = 0; mi < 4; mi++)
#pragma unroll
            for (int ni = 0; ni < 2; ni++) {
                accg[mi][ni] = __builtin_amdgcn_mfma_f32_16x16x32_bf16(af[mi], bgf[ni], accg[mi][ni], 0, 0, 0);
                accu[mi][ni] = __builtin_amdgcn_mfma_f32_16x16x32_bf16(af[mi], buf2[ni], accu[mi][ni], 0, 0, 0);
            }
        __syncthreads();      // all reads of lB done; A(k+1)/B-loads drained
        if (kk < 31) {
            GU_WRB();         // B(k+1) -> LDS
            __syncthreads();
        }
    }
#undef GU_LOADB
#undef GU_GLLA
#undef GU_WRB

    int q = lane >> 4, cl = lane & 15;
    if (routed) {
#pragma unroll
        for (int mi = 0; mi < 4; mi++) {
#pragma unroll
            for (int r = 0; r < 4; r++) {
                int row = wr * 64 + mi * 16 + q * 4 + r;
                int token = pair_token[slot0 + row];
                float s = combine[token * E_NUM + e];
#pragma unroll
                for (int ni = 0; ni < 2; ni++) {
                    float g = accg[mi][ni][r], u = accu[mi][ni][r];
                    float a = g / (1.f + expf(-g)) * u * s;
                    act_s[(size_t)(slot0 + row) * I_DIM + ci0 + wc * 32 + ni * 16 + cl] = f2b(a);
                }
            }
        }
    } else {
#pragma unroll
        for (int mi = 0; mi < 4; mi++) {
#pragma unroll
            for (int ni = 0; ni < 2; ni++) {
                int col = ci0 + wc * 32 + ni * 16 + cl;
#pragma unroll
                for (int r = 0; r < 4; r++) {
                    int row = row0 + wr * 64 + mi * 16 + q * 4 + r;
                    float g = accg[mi][ni][r], u = accu[mi][ni][r];
                    float a = g / (1.f + expf(-g)) * u;
                    act_sh[(size_t)row * IS_DIM + col] = f2b(a);
                }
            }
        }
    }
}

// ================= fused down, direct-fp32 B, 128x128 tiles =================
// blocks [0,768): routed | [768,1024): shared splitK=4
__global__ __launch_bounds__(256, 4)
void down_fused(const unsigned short* __restrict__ act_s,
                const float* __restrict__ w_down,
                const unsigned short* __restrict__ act_sh,
                const float* __restrict__ ws_down,
                const int* __restrict__ meta,
                float* __restrict__ pairpart,
                float* __restrict__ shpart) {
    int b = blockIdx.x;
    bool routed = b < 768;
    int tid = threadIdx.x, lane = tid & 63, w = tid >> 6;
    int wr = w >> 1, wc = w & 1;
    __shared__ __align__(16) unsigned short lA[2][128 * 32];
    __shared__ __align__(16) unsigned short lB[128 * 40];

    int srow = w * 32 + (lane >> 2);
    int schunk = (lane & 3) * 8;
    int aoff = (w * 32) * 32;
    int nc = (tid & 63) * 2;       // B col pair within 128
    int kg = tid >> 6;             // 0..3, owns k rows kg*8..kg*8+7

    const unsigned short* gA0;
    const float* gB;
    size_t ast;
    int kbase, n0, orow;
    float* outp;
    if (routed) {
        int tile = b >> 3;
        if (tile >= meta[0]) return;
        int e = meta[1 + tile];
        n0 = (b & 7) * 128;
        int slot0 = tile * 128;
        gA0 = act_s + (size_t)(slot0 + srow) * I_DIM + schunk;
        gB = w_down + (size_t)e * I_DIM * H_DIM + n0;
        ast = I_DIM; kbase = 0;
        outp = pairpart; orow = slot0;
    } else {
        int bb = b - 768;
        int mb = bb >> 5, nb = (bb >> 2) & 7, ks = bb & 3;
        int row0 = mb * 128;
        n0 = nb * 128;
        gA0 = act_sh + (size_t)(row0 + srow) * IS_DIM + schunk;
        gB = ws_down + n0;
        ast = IS_DIM; kbase = ks * 512;
        outp = shpart + ((size_t)ks << 20); orow = row0;
    }

    f32x4 acc[4][4];
#pragma unroll
    for (int i = 0; i < 4; i++)
#pragma unroll
        for (int j = 0; j < 4; j++)
#pragma unroll
            for (int r = 0; r < 4; r++) acc[i][j][r] = 0.f;

    float2 vb[8];

#define DN_LOADB(KK)                                                    \
    do {                                                                \
        size_t kb = (size_t)(kbase + (KK) * 32 + kg * 8);               \
        _Pragma("unroll")                                               \
        for (int j = 0; j < 8; j++)                                     \
            vb[j] = *reinterpret_cast<const float2*>(&gB[(kb + j) * H_DIM + nc]); \
    } while (0)

#define DN_GLLA(KK, BSEL)                                               \
    do {                                                                \
        size_t _k0 = (size_t)kbase + (size_t)(KK) * 32;                 \
        unsigned short* _a = &lA[BSEL][aoff];                           \
        gll16(gA0 + _k0, _a);                                           \
        gll16(gA0 + 16 * ast + _k0, _a + 16 * 32);                      \
    } while (0)

#define DN_WRB()                                                        \
    do {                                                                \
        uint4 u;                                                        \
        u.x = cvt2(vb[0].x, vb[1].x); u.y = cvt2(vb[2].x, vb[3].x);     \
        u.z = cvt2(vb[4].x, vb[5].x); u.w = cvt2(vb[6].x, vb[7].x);     \
        *reinterpret_cast<uint4*>(&lB[nc * 40 + kg * 8]) = u;           \
        u.x = cvt2(vb[0].y, vb[1].y); u.y = cvt2(vb[2].y, vb[3].y);     \
        u.z = cvt2(vb[4].y, vb[5].y); u.w = cvt2(vb[6].y, vb[7].y);     \
        *reinterpret_cast<uint4*>(&lB[(nc + 1) * 40 + kg * 8]) = u;     \
    } while (0)

    DN_GLLA(0, 0);
    DN_LOADB(0);
    __syncthreads();
    DN_WRB();
    __syncthreads();
    for (int kk = 0; kk < 16; kk++) {
        int cur = kk & 1;
        if (kk < 15) { DN_GLLA(kk + 1, cur ^ 1); DN_LOADB(kk + 1); }
        bf16x8 af[4], bf[4];
#pragma unroll
        for (int mi = 0; mi < 4; mi++)
            af[mi] = *reinterpret_cast<const bf16x8*>(
                &lA[cur][(wr * 64 + mi * 16 + (lane & 15)) * 32 + (lane >> 4) * 8]);
#pragma unroll
        for (int ni = 0; ni < 4; ni++)
            bf[ni] = *reinterpret_cast<const bf16x8*>(
                &lB[(wc * 64 + ni * 16 + (lane & 15)) * 40 + (lane >> 4) * 8]);
#pragma unroll
        for (int mi = 0; mi < 4; mi++)
#pragma unroll
            for (int ni = 0; ni < 4; ni++)
                acc[mi][ni] = __builtin_amdgcn_mfma_f32_16x16x32_bf16(af[mi], bf[ni], acc[mi][ni], 0, 0, 0);
        __syncthreads();
        if (kk < 15) {
            DN_WRB();
            __syncthreads();
        }
    }
#undef DN_LOADB
#undef DN_GLLA
#undef DN_WRB

    int q = lane >> 4, cl = lane & 15;
#pragma unroll
    for (int mi = 0; mi < 4; mi++) {
#pragma unroll
        for (int ni = 0; ni < 4; ni++) {
            int col = n0 + wc * 64 + ni * 16 + cl;
#pragma unroll
            for (int r = 0; r < 4; r++) {
                int row = orow + wr * 64 + mi * 16 + q * 4 + r;
                outp[(size_t)row * H_DIM + col] = acc[mi][ni][r];
            }
        }
    }
}

// ---------------- final combine ----------------
__global__ void final_combine(const float* __restrict__ pairpart,
                              const float* __restrict__ shpart,
                              const int* __restrict__ slot_of,
                              float* __restrict__ out) {
    int t = blockIdx.x;
    int h = threadIdx.x * 4;
    float4 o = reinterpret_cast<const float4*>(shpart + (size_t)t * H_DIM + h)[0];
#pragma unroll
    for (int ks = 1; ks < 4; ks++) {
        float4 v = reinterpret_cast<const float4*>(shpart + ((size_t)ks << 20) + (size_t)t * H_DIM + h)[0];
        o.x += v.x; o.y += v.y; o.z += v.z; o.w += v.w;
    }
#pragma unroll
    for (int r = 0; r < 8; r++) {
        int s = slot_of[t * 8 + r];
        float4 v = reinterpret_cast<const float4*>(pairpart + (size_t)s * H_DIM + h)[0];
        o.x += v.x; o.y += v.y; o.z += v.z; o.w += v.w;
    }
    reinterpret_cast<float4*>(out + (size_t)t * H_DIM + h)[0] = o;
}

// ================= FALLBACK PATH (round-1 kernels, small ws) =================

__global__ void cvt_x_kernel(const float* __restrict__ x, unsigned short* __restrict__ xb) {
    int i = blockIdx.x * 256 + threadIdx.x;
    float4 v = reinterpret_cast<const float4*>(x)[i];
    uint2 o;
    o.x = (uint32_t)f2b(v.x) | ((uint32_t)f2b(v.y) << 16);
    o.y = (uint32_t)f2b(v.z) | ((uint32_t)f2b(v.w) << 16);
    reinterpret_cast<uint2*>(xb)[i] = o;
}

__global__ void routing_kernel(const float* __restrict__ x,
                               const float* __restrict__ gate_w,
                               const float* __restrict__ e_bias,
                               float* __restrict__ combine,
                               int* __restrict__ topk) {
    int t = blockIdx.x;
    routing_wave(x, gate_w, e_bias, combine, topk, t);
}

__global__ __launch_bounds__(256, 2)
void gateup_kernel(const unsigned short* __restrict__ xb,
                   const float* __restrict__ w_gate,
                   const float* __restrict__ w_up,
                   const float* __restrict__ ws_gate,
                   const float* __restrict__ ws_up,
                   const float* __restrict__ combine,
                   unsigned short* __restrict__ act) {
    int mb = blockIdx.x, cb = blockIdx.y;
    int row0 = mb * 128, c0 = cb * 128;
    const float *bg, *bu;
    int bstride, eidx;
    if (c0 < NCOL_R) {
        int e = c0 >> 9, ci = c0 & 511;
        bg = w_gate + (size_t)e * H_DIM * I_DIM + ci;
        bu = w_up   + (size_t)e * H_DIM * I_DIM + ci;
        bstride = I_DIM; eidx = e;
    } else {
        int ci = c0 - NCOL_R;
        bg = ws_gate + ci; bu = ws_up + ci;
        bstride = IS_DIM; eidx = -1;
    }
    __shared__ __align__(16) unsigned short lA[128*32];
    __shared__ __align__(16) unsigned short lBg[128*32];
    __shared__ __align__(16) unsigned short lBu[128*32];
    int tid = threadIdx.x, lane = tid & 63, w = tid >> 6;
    int wr = w >> 1, wc = w & 1;
    f32x4 accg[4][4], accu[4][4];
#pragma unroll
    for (int i = 0; i < 4; i++)
#pragma unroll
        for (int j = 0; j < 4; j++)
#pragma unroll
            for (int r = 0; r < 4; r++) { accg[i][j][r] = 0.f; accu[i][j][r] = 0.f; }
    int ar = tid >> 2, ak = (tid & 3) * 8;
    int bn = tid & 127, bkg = (tid >> 7) * 16;
    for (int kk = 0; kk < H_DIM / 32; kk++) {
        int k0 = kk * 32;
        __syncthreads();
        *reinterpret_cast<uint4*>(&lA[ar*32 + ak]) =
            *reinterpret_cast<const uint4*>(xb + (size_t)(row0 + ar) * H_DIM + k0 + ak);
        *reinterpret_cast<uint4*>(&lA[(ar+64)*32 + ak]) =
            *reinterpret_cast<const uint4*>(xb + (size_t)(row0 + ar + 64) * H_DIM + k0 + ak);
#pragma unroll
        for (int p = 0; p < 4; p++) {
            int kb = bkg + p * 4;
            const float* pg = bg + (size_t)(k0 + kb) * bstride + bn;
            uint2 dg;
            dg.x = (uint32_t)f2b(pg[0])         | ((uint32_t)f2b(pg[bstride])   << 16);
            dg.y = (uint32_t)f2b(pg[2*bstride]) | ((uint32_t)f2b(pg[3*bstride]) << 16);
            *reinterpret_cast<uint2*>(&lBg[bn*32 + kb]) = dg;
            const float* pu = bu + (size_t)(k0 + kb) * bstride + bn;
            uint2 du;
            du.x = (uint32_t)f2b(pu[0])         | ((uint32_t)f2b(pu[bstride])   << 16);
            du.y = (uint32_t)f2b(pu[2*bstride]) | ((uint32_t)f2b(pu[3*bstride]) << 16);
            *reinterpret_cast<uint2*>(&lBu[bn*32 + kb]) = du;
        }
        __syncthreads();
        bf16x8 af[4], bgf[4], buf2[4];
#pragma unroll
        for (int mi = 0; mi < 4; mi++)
            af[mi] = *reinterpret_cast<const bf16x8*>(&lA[(wr*64 + mi*16 + (lane & 15))*32 + (lane >> 4)*8]);
#pragma unroll
        for (int ni = 0; ni < 4; ni++) {
            int nn = (wc*64 + ni*16 + (lane & 15))*32 + (lane >> 4)*8;
            bgf[ni]  = *reinterpret_cast<const bf16x8*>(&lBg[nn]);
            buf2[ni] = *reinterpret_cast<const bf16x8*>(&lBu[nn]);
        }
#pragma unroll
        for (int mi = 0; mi < 4; mi++)
#pragma unroll
            for (int ni = 0; ni < 4; ni++) {
                accg[mi][ni] = __builtin_amdgcn_mfma_f32_16x16x32_bf16(af[mi], bgf[ni],  accg[mi][ni], 0, 0, 0);
                accu[mi][ni] = __builtin_amdgcn_mfma_f32_16x16x32_bf16(af[mi], buf2[ni], accu[mi][ni], 0, 0, 0);
            }
    }
    int q = lane >> 4, cl = lane & 15;
#pragma unroll
    for (int mi = 0; mi < 4; mi++) {
#pragma unroll
        for (int ni = 0; ni < 4; ni++) {
            int colg = c0 + wc*64 + ni*16 + cl;
#pragma unroll
            for (int r = 0; r < 4; r++) {
                int row = row0 + wr*64 + mi*16 + q*4 + r;
                float g = accg[mi][ni][r], u = accu[mi][ni][r];
                float a = g / (1.f + expf(-g)) * u;
                float s = (eidx >= 0) ? combine[row * E_NUM + eidx] : 1.0f;
                act[(size_t)row * NCOL_T + colg] = f2b(a * s);
            }
        }
    }
}

__global__ __launch_bounds__(256, 2)
void down_kernel(const unsigned short* __restrict__ act,
                 const float* __restrict__ w_down,
                 const float* __restrict__ ws_down,
                 float* __restrict__ partials) {
    int mb = blockIdx.x, nb = blockIdx.y, ks = blockIdx.z;
    int row0 = mb * 128, n0 = nb * 128;
    __shared__ __align__(16) unsigned short lA[128*32];
    __shared__ __align__(16) unsigned short lB[128*32];
    int tid = threadIdx.x, lane = tid & 63, w = tid >> 6;
    int wr = w >> 1, wc = w & 1;
    f32x4 acc[4][4];
#pragma unroll
    for (int i = 0; i < 4; i++)
#pragma unroll
        for (int j = 0; j < 4; j++)
#pragma unroll
            for (int r = 0; r < 4; r++) acc[i][j][r] = 0.f;
    int ar = tid >> 2, ak = (tid & 3) * 8;
    int bn = tid & 127, bkg = (tid >> 7) * 16;
    for (int kk = 0; kk < 144; kk++) {
        int k0 = ks * 4608 + kk * 32;
        const float* bb = (k0 < NCOL_R) ? (w_down + (size_t)k0 * H_DIM)
                                        : (ws_down + (size_t)(k0 - NCOL_R) * H_DIM);
        __syncthreads();
        *reinterpret_cast<uint4*>(&lA[ar*32 + ak]) =
            *reinterpret_cast<const uint4*>(act + (size_t)(row0 + ar) * NCOL_T + k0 + ak);
        *reinterpret_cast<uint4*>(&lA[(ar+64)*32 + ak]) =
            *reinterpret_cast<const uint4*>(act + (size_t)(row0 + ar + 64) * NCOL_T + k0 + ak);
#pragma unroll
        for (int p = 0; p < 4; p++) {
            int kb = bkg + p * 4;
            const float* pb = bb + (size_t)kb * H_DIM + n0 + bn;
            uint2 d;
            d.x = (uint32_t)f2b(pb[0])       | ((uint32_t)f2b(pb[H_DIM])   << 16);
            d.y = (uint32_t)f2b(pb[2*H_DIM]) | ((uint32_t)f2b(pb[3*H_DIM]) << 16);
            *reinterpret_cast<uint2*>(&lB[bn*32 + kb]) = d;
        }
        __syncthreads();
        bf16x8 af[4], bf[4];
#pragma unroll
        for (int mi = 0; mi < 4; mi++)
            af[mi] = *reinterpret_cast<const bf16x8*>(&lA[(wr*64 + mi*16 + (lane & 15))*32 + (lane >> 4)*8]);
#pragma unroll
        for (int ni = 0; ni < 4; ni++)
            bf[ni] = *reinterpret_cast<const bf16x8*>(&lB[(wc*64 + ni*16 + (lane & 15))*32 + (lane >> 4)*8]);
#pragma unroll
        for (int mi = 0; mi < 4; mi++)
#pragma unroll
            for (int ni = 0; ni < 4; ni++)
                acc[mi][ni] = __builtin_amdgcn_mfma_f32_16x16x32_bf16(af[mi], bf[ni], acc[mi][ni], 0, 0, 0);
    }
    float* pout = partials + ((size_t)ks << 20);
    int q = lane >> 4, cl = lane & 15;
#pragma unroll
    for (int mi = 0; mi < 4; mi++) {
#pragma unroll
        for (int ni = 0; ni < 4; ni++) {
            int col = n0 + wc*64 + ni*16 + cl;
#pragma unroll
            for (int r = 0; r < 4; r++) {
                int row = row0 + wr*64 + mi*16 + q*4 + r;
                pout[(size_t)row * H_DIM + col] = acc[mi][ni][r];
            }
        }
    }
}

__global__ void reduce_kernel(const float* __restrict__ p, float* __restrict__ out) {
    int i = blockIdx.x * 256 + threadIdx.x;
    float4 a = reinterpret_cast<const float4*>(p)[i];
    float4 b = reinterpret_cast<const float4*>(p + (size_t)1048576)[i];
    float4 c = reinterpret_cast<const float4*>(p + (size_t)2097152)[i];
    float4 d = reinterpret_cast<const float4*>(p + (size_t)3145728)[i];
    float4 o;
    o.x = a.x + b.x + c.x + d.x;
    o.y = a.y + b.y + c.y + d.y;
    o.z = a.z + b.z + c.z + d.z;
    o.w = a.w + b.w + c.w + d.w;
    reinterpret_cast<float4*>(out)[i] = o;
}

extern "C" void kernel_launch(void* const* d_in, const int* in_sizes, int n_in,
                              void* d_out, int out_size, void* d_ws, size_t ws_size,
                              hipStream_t stream) {
    const float* x       = (const float*)d_in[0];
    const float* gate_w  = (const float*)d_in[1];
    const float* e_bias  = (const float*)d_in[2];
    const float* w_gate  = (const float*)d_in[3];
    const float* w_up    = (const float*)d_in[4];
    const float* w_down  = (const float*)d_in[5];
    const float* ws_gate = (const float*)d_in[6];
    const float* ws_up   = (const float*)d_in[7];
    const float* ws_down = (const float*)d_in[8];
    float* out = (float*)d_out;

    char* ws = (char*)d_ws;
    bool fast = ws_size >= 170000384ull;   // ws_size constant across calls -> capture-safe branch

    if (fast) {
        float* combine      = (float*)(ws);                       // 131072
        int*   topk         = (int*)(ws + 131072);                // 32768
        int*   meta         = (int*)(ws + 163840);                // 512
        int*   pair_token   = (int*)(ws + 164352);                // 49152
        int*   slot_of      = (int*)(ws + 213504);                // 32768
        unsigned short* xb  = (unsigned short*)(ws + 262144);     // 2 MB
        unsigned short* act_s  = (unsigned short*)(ws + 2359296);    // 12.6 MB
        unsigned short* act_sh = (unsigned short*)(ws + 14942208);   // 4 MB
        float* pairpart     = (float*)(ws + 19136512);               // 50.33 MB
        float* shpart       = (float*)(ws + 69468160);               // 16 MB, ends 86245376

        prep1_kernel<<<512, 256, 0, stream>>>(x, gate_w, e_bias, xb, combine, topk);
        listbuild_kernel<<<1, 1024, 0, stream>>>(topk, meta, pair_token, slot_of);
        gateup_fused<<<1024, 256, 0, stream>>>(xb, w_gate, w_up, ws_gate, ws_up,
                                               combine, pair_token, meta, act_s, act_sh);
        down_fused<<<1024, 256, 0, stream>>>(act_s, w_down, act_sh, ws_down, meta,
                                             pairpart, shpart);
        final_combine<<<1024, 256, 0, stream>>>(pairpart, shpart, slot_of, out);
    } else {
        float* combine     = (float*)(ws);
        int*   topk        = (int*)(ws + 131072);
        unsigned short* xb = (unsigned short*)(ws + 262144);
        unsigned short* act= (unsigned short*)(ws + 2359296);
        float* partials    = (float*)(ws + 40108032);

        cvt_x_kernel<<<1024, 256, 0, stream>>>(x, xb);
        routing_kernel<<<1024, 64, 0, stream>>>(x, gate_w, e_bias, combine, topk);
        gateup_kernel<<<dim3(8, 144), 256, 0, stream>>>(xb, w_gate, w_up, ws_gate, ws_up, combine, act);
        down_kernel<<<dim3(8, 8, 4), 256, 0, stream>>>(act, w_down, ws_down, partials);
        reduce_kernel<<<1024, 256, 0, stream>>>(partials, out);
    }
}